// Round 1
// baseline (158.947 us; speedup 1.0000x reference)
//
#include <hip/hip_runtime.h>
#include <hip/hip_bf16.h>

#define BATCH 8
#define SEQ   1024
#define DMODEL 512
#define NH    8
#define DH    64
#define MTOK  (BATCH*SEQ)      // 8192
#define LUTD  5120

typedef __attribute__((ext_vector_type(8))) _Float16 half8;
typedef __attribute__((ext_vector_type(4))) _Float16 half4;
typedef __attribute__((ext_vector_type(4))) float    f32x4;

// ---------------- prep: cast x to fp16 ----------------
__global__ void prep_cast_x(const float* __restrict__ x, _Float16* __restrict__ xh) {
  int g = blockIdx.x * 256 + threadIdx.x;           // 1,048,576 threads, 4 f32 each
  float4 v = reinterpret_cast<const float4*>(x)[g];
  half4 u;
  u[0] = (_Float16)v.x; u[1] = (_Float16)v.y; u[2] = (_Float16)v.z; u[3] = (_Float16)v.w;
  reinterpret_cast<half4*>(xh)[g] = u;
}

// ---------------- prep: weights + bias concat ----------------
__global__ void prep_w(const float* __restrict__ qw, const float* __restrict__ kw,
                       const float* __restrict__ vw, const float* __restrict__ ow,
                       const float* __restrict__ qb, const float* __restrict__ kb,
                       const float* __restrict__ vb,
                       _Float16* __restrict__ wqkvh, _Float16* __restrict__ owh,
                       float* __restrict__ qkvbias) {
  int g = blockIdx.x * 256 + threadIdx.x;
  if (g < 196608) {                       // 3 * 65536 float4s of qkv weights
    const float* src = (g < 65536) ? qw : (g < 131072) ? kw : vw;
    int lg = g & 65535;
    float4 v = reinterpret_cast<const float4*>(src)[lg];
    half4 u;
    u[0] = (_Float16)v.x; u[1] = (_Float16)v.y; u[2] = (_Float16)v.z; u[3] = (_Float16)v.w;
    reinterpret_cast<half4*>(wqkvh)[g] = u;
  } else if (g < 262144) {                // 65536 float4s of ow
    int lg = g - 196608;
    float4 v = reinterpret_cast<const float4*>(ow)[lg];
    half4 u;
    u[0] = (_Float16)v.x; u[1] = (_Float16)v.y; u[2] = (_Float16)v.z; u[3] = (_Float16)v.w;
    reinterpret_cast<half4*>(owh)[lg] = u;
  } else if (g < 262528) {                // 384 float4s of qkv bias concat
    int lg = g - 262144;
    const float* src = (lg < 128) ? qb : (lg < 256) ? kb : vb;
    int ll = lg & 127;
    reinterpret_cast<float4*>(qkvbias)[lg] = reinterpret_cast<const float4*>(src)[ll];
  }
}

// ---------------- prep: per-head distance-bias LUT ----------------
// bin = #{t : edges[t] < dist} (searchsorted side='left'), dist integer 0..5119
__global__ void prep_lut(const float* __restrict__ edges, const float* __restrict__ demb,
                         _Float16* __restrict__ lut) {
  int h = blockIdx.x / 20;
  int d = (blockIdx.x % 20) * 256 + threadIdx.x;
  float fd = (float)d;
  int bin = 0;
#pragma unroll
  for (int t = 0; t < 31; ++t) bin += (edges[t] < fd) ? 1 : 0;
  lut[h * LUTD + d] = (_Float16)demb[bin * NH + h];
}

// ---------------- QKV projection GEMM ----------------
// C[m][n] = sum_k X[m][k] * Wcat[n][k] + bias[n];  M=8192, N=1536, K=512
// scatter into qkv[p][b][h][n][d] fp16 (p: 0=Q,1=K,2=V)
__global__ __launch_bounds__(256) void qkv_gemm(const _Float16* __restrict__ xh,
                                                const _Float16* __restrict__ wh,
                                                const float* __restrict__ bias,
                                                _Float16* __restrict__ qkv) {
  __shared__ __attribute__((aligned(16))) _Float16 As[64 * 40];
  __shared__ __attribute__((aligned(16))) _Float16 Bs[64 * 40];
  const int m0 = blockIdx.x * 64, n0 = blockIdx.y * 64;
  const int tid = threadIdx.x, w = tid >> 6, lane = tid & 63;
  const int lr = lane & 15, lg = lane >> 4;
  f32x4 acc[4] = {};
  const int sr = tid >> 2, ss = (tid & 3) * 8;
  for (int k0 = 0; k0 < 512; k0 += 32) {
    *reinterpret_cast<uint4*>(&As[sr * 40 + ss]) =
        *reinterpret_cast<const uint4*>(&xh[(m0 + sr) * 512 + k0 + ss]);
    *reinterpret_cast<uint4*>(&Bs[sr * 40 + ss]) =
        *reinterpret_cast<const uint4*>(&wh[(n0 + sr) * 512 + k0 + ss]);
    __syncthreads();
    half8 a = *reinterpret_cast<const half8*>(&As[(w * 16 + lr) * 40 + lg * 8]);
#pragma unroll
    for (int ct = 0; ct < 4; ++ct) {
      half8 bf = *reinterpret_cast<const half8*>(&Bs[(ct * 16 + lr) * 40 + lg * 8]);
      acc[ct] = __builtin_amdgcn_mfma_f32_16x16x32_f16(a, bf, acc[ct], 0, 0, 0);
    }
    __syncthreads();
  }
#pragma unroll
  for (int ct = 0; ct < 4; ++ct) {
    int n = n0 + ct * 16 + lr;
    float bv = bias[n];
    int p = n >> 9, c = n & 511, h = c >> 6, d = c & 63;
#pragma unroll
    for (int r = 0; r < 4; ++r) {
      int m = m0 + w * 16 + lg * 4 + r;
      int bb = m >> 10, nn = m & 1023;
      qkv[p * 4194304 + ((bb * NH + h) * SEQ + nn) * DH + d] = (_Float16)(acc[ct][r] + bv);
    }
  }
}

// ---------------- fused attention (flash-style) ----------------
__global__ __launch_bounds__(256) void attn_kernel(const _Float16* __restrict__ qkv,
                                                   const int* __restrict__ positions,
                                                   const float* __restrict__ mask,
                                                   const _Float16* __restrict__ lutg,
                                                   const float* __restrict__ order_bias,
                                                   _Float16* __restrict__ aout) {
  __shared__ __attribute__((aligned(16))) _Float16 lutl[LUTD];       // 10 KB
  __shared__ __attribute__((aligned(16))) _Float16 Ks[64 * 72];      // 9 KB
  __shared__ __attribute__((aligned(16))) _Float16 Vts[64 * 72];     // 9 KB (V transposed)
  __shared__ __attribute__((aligned(16))) _Float16 Pl[64 * 72];      // 9 KB
  __shared__ int posq[64];
  __shared__ int poskv[64];
  __shared__ float maskkv[64];
  __shared__ float maskq[64];
  const int qt = blockIdx.x, h = blockIdx.y, b = blockIdx.z;
  const int tid = threadIdx.x, w = tid >> 6, lane = tid & 63;
  const int lr = lane & 15, lg = lane >> 4;

  for (int i = tid; i < LUTD / 2; i += 256)   // copy LUT as dwords (2 halfs)
    reinterpret_cast<unsigned int*>(lutl)[i] =
        reinterpret_cast<const unsigned int*>(lutg)[h * (LUTD / 2) + i];
  if (tid < 64) {
    posq[tid] = positions[b * SEQ + qt * 64 + tid];
    maskq[tid] = mask[b * SEQ + qt * 64 + tid];
  }
  const _Float16* Qg = qkv + ((b * NH + h) * SEQ) * DH;
  const _Float16* Kg = qkv + 4194304 + ((b * NH + h) * SEQ) * DH;
  const _Float16* Vg = qkv + 8388608 + ((b * NH + h) * SEQ) * DH;
  half8 qf[2];
#pragma unroll
  for (int ks = 0; ks < 2; ++ks)
    qf[ks] = *reinterpret_cast<const half8*>(&Qg[(qt * 64 + w * 16 + lr) * DH + ks * 32 + lg * 8]);
  const float obh = order_bias[h];
  float m_run[4], l_run[4];
  f32x4 o[4] = {};
#pragma unroll
  for (int r = 0; r < 4; ++r) { m_run[r] = -INFINITY; l_run[r] = 0.f; }
  __syncthreads();

  for (int kt = 0; kt < 16; ++kt) {
    const int kv0 = kt * 64;
    {
      int r = tid >> 2, s = (tid & 3) * 16;
      *reinterpret_cast<uint4*>(&Ks[r * 72 + s]) =
          *reinterpret_cast<const uint4*>(&Kg[(kv0 + r) * DH + s]);
      *reinterpret_cast<uint4*>(&Ks[r * 72 + s + 8]) =
          *reinterpret_cast<const uint4*>(&Kg[(kv0 + r) * DH + s + 8]);
    }
    for (int idx = tid; idx < 4096; idx += 256) {       // V transpose staging
      int j = idx >> 6, d = idx & 63;
      Vts[d * 72 + j] = Vg[(kv0 + j) * DH + d];
    }
    if (tid < 64) {
      poskv[tid] = positions[b * SEQ + kv0 + tid];
      maskkv[tid] = mask[b * SEQ + kv0 + tid];
    }
    __syncthreads();

    f32x4 s4[4] = {};
#pragma unroll
    for (int ct = 0; ct < 4; ++ct)
#pragma unroll
      for (int ks = 0; ks < 2; ++ks) {
        half8 bf = *reinterpret_cast<const half8*>(&Ks[(ct * 16 + lr) * 72 + ks * 32 + lg * 8]);
        s4[ct] = __builtin_amdgcn_mfma_f32_16x16x32_f16(qf[ks], bf, s4[ct], 0, 0, 0);
      }

    int pi[4];
#pragma unroll
    for (int r = 0; r < 4; ++r) pi[r] = posq[w * 16 + lg * 4 + r];
#pragma unroll
    for (int ct = 0; ct < 4; ++ct) {
      int pj = poskv[ct * 16 + lr];
      float mv = maskkv[ct * 16 + lr];
#pragma unroll
      for (int r = 0; r < 4; ++r) {
        int dist = pi[r] - pj; dist = dist < 0 ? -dist : dist;
        float sv = s4[ct][r] * 0.125f + (float)lutl[dist] +
                   ((pj > pi[r]) ? 0.5f : -0.5f) * obh;
        s4[ct][r] = (mv == 0.f) ? -1.0e9f : sv;
      }
    }
    // online softmax (rows live in lanes: row = w*16 + lg*4 + r, cols = 16 lanes x 4 tiles)
#pragma unroll
    for (int r = 0; r < 4; ++r) {
      float m_ = fmaxf(fmaxf(s4[0][r], s4[1][r]), fmaxf(s4[2][r], s4[3][r]));
      m_ = fmaxf(m_, __shfl_xor(m_, 1)); m_ = fmaxf(m_, __shfl_xor(m_, 2));
      m_ = fmaxf(m_, __shfl_xor(m_, 4)); m_ = fmaxf(m_, __shfl_xor(m_, 8));
      float newm = fmaxf(m_run[r], m_);
      float alpha = __expf(m_run[r] - newm);
      float sum_ = 0.f;
#pragma unroll
      for (int ct = 0; ct < 4; ++ct) {
        float p = __expf(s4[ct][r] - newm);
        s4[ct][r] = p; sum_ += p;
      }
      sum_ += __shfl_xor(sum_, 1); sum_ += __shfl_xor(sum_, 2);
      sum_ += __shfl_xor(sum_, 4); sum_ += __shfl_xor(sum_, 8);
      l_run[r] = l_run[r] * alpha + sum_;
      m_run[r] = newm;
#pragma unroll
      for (int dt = 0; dt < 4; ++dt) o[dt][r] *= alpha;
    }
    // P (C-layout) -> LDS for A-fragment reads
#pragma unroll
    for (int ct = 0; ct < 4; ++ct)
#pragma unroll
      for (int r = 0; r < 4; ++r)
        Pl[(w * 16 + lg * 4 + r) * 72 + ct * 16 + lr] = (_Float16)s4[ct][r];
    __syncthreads();
#pragma unroll
    for (int dt = 0; dt < 4; ++dt)
#pragma unroll
      for (int ks = 0; ks < 2; ++ks) {
        half8 pa = *reinterpret_cast<const half8*>(&Pl[(w * 16 + lr) * 72 + ks * 32 + lg * 8]);
        half8 vb = *reinterpret_cast<const half8*>(&Vts[(dt * 16 + lr) * 72 + ks * 32 + lg * 8]);
        o[dt] = __builtin_amdgcn_mfma_f32_16x16x32_f16(pa, vb, o[dt], 0, 0, 0);
      }
    __syncthreads();
  }
#pragma unroll
  for (int dt = 0; dt < 4; ++dt) {
    int d = dt * 16 + lr;
#pragma unroll
    for (int r = 0; r < 4; ++r) {
      int qrow = w * 16 + lg * 4 + r;
      float val = (o[dt][r] / l_run[r]) * maskq[qrow];
      aout[(b * SEQ + qt * 64 + qrow) * DMODEL + h * DH + d] = (_Float16)val;
    }
  }
}

// ---------------- output projection GEMM ----------------
__global__ __launch_bounds__(256) void out_gemm(const _Float16* __restrict__ ah,
                                                const _Float16* __restrict__ wh,
                                                const float* __restrict__ ob,
                                                float* __restrict__ out) {
  __shared__ __attribute__((aligned(16))) _Float16 As[64 * 40];
  __shared__ __attribute__((aligned(16))) _Float16 Bs[64 * 40];
  const int m0 = blockIdx.x * 64, n0 = blockIdx.y * 64;
  const int tid = threadIdx.x, w = tid >> 6, lane = tid & 63;
  const int lr = lane & 15, lg = lane >> 4;
  f32x4 acc[4] = {};
  const int sr = tid >> 2, ss = (tid & 3) * 8;
  for (int k0 = 0; k0 < 512; k0 += 32) {
    *reinterpret_cast<uint4*>(&As[sr * 40 + ss]) =
        *reinterpret_cast<const uint4*>(&ah[(m0 + sr) * 512 + k0 + ss]);
    *reinterpret_cast<uint4*>(&Bs[sr * 40 + ss]) =
        *reinterpret_cast<const uint4*>(&wh[(n0 + sr) * 512 + k0 + ss]);
    __syncthreads();
    half8 a = *reinterpret_cast<const half8*>(&As[(w * 16 + lr) * 40 + lg * 8]);
#pragma unroll
    for (int ct = 0; ct < 4; ++ct) {
      half8 bf = *reinterpret_cast<const half8*>(&Bs[(ct * 16 + lr) * 40 + lg * 8]);
      acc[ct] = __builtin_amdgcn_mfma_f32_16x16x32_f16(a, bf, acc[ct], 0, 0, 0);
    }
    __syncthreads();
  }
#pragma unroll
  for (int ct = 0; ct < 4; ++ct) {
    int n = n0 + ct * 16 + lr;
    float bv = ob[n];
#pragma unroll
    for (int r = 0; r < 4; ++r) {
      int m = m0 + w * 16 + lg * 4 + r;
      out[m * DMODEL + n] = acc[ct][r] + bv;
    }
  }
}

extern "C" void kernel_launch(void* const* d_in, const int* in_sizes, int n_in,
                              void* d_out, int out_size, void* d_ws, size_t ws_size,
                              hipStream_t stream) {
  const float* x         = (const float*)d_in[0];
  const int*   positions = (const int*)d_in[1];
  const float* mask      = (const float*)d_in[2];
  const float* qw        = (const float*)d_in[3];
  const float* qb        = (const float*)d_in[4];
  const float* kw        = (const float*)d_in[5];
  const float* kb        = (const float*)d_in[6];
  const float* vw        = (const float*)d_in[7];
  const float* vb        = (const float*)d_in[8];
  const float* ow        = (const float*)d_in[9];
  const float* ob        = (const float*)d_in[10];
  const float* demb      = (const float*)d_in[11];
  const float* obias     = (const float*)d_in[12];
  const float* edges     = (const float*)d_in[13];

  char* ws = (char*)d_ws;
  _Float16* xh     = (_Float16*)(ws);                    // 8,388,608 B
  _Float16* qkv    = (_Float16*)(ws + 8388608);          // 25,165,824 B (Q,K,V)
  _Float16* aouth  = (_Float16*)(ws + 33554432);         // 8,388,608 B
  _Float16* wqkvh  = (_Float16*)(ws + 41943040);         // 1,572,864 B
  _Float16* owh    = (_Float16*)(ws + 43515904);         // 524,288 B
  float*    qkvbias= (float*)(ws + 44040192);            // 6,144 B
  _Float16* lut    = (_Float16*)(ws + 44046336);         // 81,920 B
  float*    outp   = (float*)d_out;

  prep_cast_x<<<4096, 256, 0, stream>>>(x, xh);
  prep_w<<<1026, 256, 0, stream>>>(qw, kw, vw, ow, qb, kb, vb, wqkvh, owh, qkvbias);
  prep_lut<<<160, 256, 0, stream>>>(edges, demb, lut);
  qkv_gemm<<<dim3(128, 24), 256, 0, stream>>>(xh, wqkvh, qkvbias, qkv);
  attn_kernel<<<dim3(16, NH, BATCH), 256, 0, stream>>>(qkv, positions, mask, lut, obias, aouth);
  out_gemm<<<dim3(128, 8), 256, 0, stream>>>(aouth, owh, ob, outp);
}

// Round 2
// 139.835 us; speedup vs baseline: 1.1367x; 1.1367x over previous
//
#include <hip/hip_runtime.h>
#include <hip/hip_bf16.h>

#define BATCH 8
#define SEQ   1024
#define DMODEL 512
#define NH    8
#define DH    64
#define MTOK  (BATCH*SEQ)      // 8192

typedef __attribute__((ext_vector_type(8))) _Float16 half8;
typedef __attribute__((ext_vector_type(4))) _Float16 half4;
typedef __attribute__((ext_vector_type(4))) float    f32x4;

// ---------------- prep: cast x to fp16 ----------------
__global__ void prep_cast_x(const float* __restrict__ x, _Float16* __restrict__ xh) {
  int g = blockIdx.x * 256 + threadIdx.x;
  float4 v = reinterpret_cast<const float4*>(x)[g];
  half4 u;
  u[0] = (_Float16)v.x; u[1] = (_Float16)v.y; u[2] = (_Float16)v.z; u[3] = (_Float16)v.w;
  reinterpret_cast<half4*>(xh)[g] = u;
}

// ---------------- prep: weights + bias concat ----------------
__global__ void prep_w(const float* __restrict__ qw, const float* __restrict__ kw,
                       const float* __restrict__ vw, const float* __restrict__ ow,
                       const float* __restrict__ qb, const float* __restrict__ kb,
                       const float* __restrict__ vb,
                       _Float16* __restrict__ wqkvh, _Float16* __restrict__ owh,
                       float* __restrict__ qkvbias) {
  int g = blockIdx.x * 256 + threadIdx.x;
  if (g < 196608) {
    const float* src = (g < 65536) ? qw : (g < 131072) ? kw : vw;
    int lg = g & 65535;
    float4 v = reinterpret_cast<const float4*>(src)[lg];
    half4 u;
    u[0] = (_Float16)v.x; u[1] = (_Float16)v.y; u[2] = (_Float16)v.z; u[3] = (_Float16)v.w;
    reinterpret_cast<half4*>(wqkvh)[g] = u;
  } else if (g < 262144) {
    int lg = g - 196608;
    float4 v = reinterpret_cast<const float4*>(ow)[lg];
    half4 u;
    u[0] = (_Float16)v.x; u[1] = (_Float16)v.y; u[2] = (_Float16)v.z; u[3] = (_Float16)v.w;
    reinterpret_cast<half4*>(owh)[lg] = u;
  } else if (g < 262528) {
    int lg = g - 262144;
    const float* src = (lg < 128) ? qb : (lg < 256) ? kb : vb;
    int ll = lg & 127;
    reinterpret_cast<float4*>(qkvbias)[lg] = reinterpret_cast<const float4*>(src)[ll];
  }
}

// ---------------- prep: bins u8[b][j][i] (symmetric in i,j) ----------------
// bin = #{t : edges[t] < |pos_j - pos_i|}  (searchsorted side='left', clip to 31 implicit)
__global__ void prep_bins(const int* __restrict__ positions, const float* __restrict__ edges,
                          unsigned char* __restrict__ bins) {
  __shared__ float eg[31];
  if (threadIdx.x < 31) eg[threadIdx.x] = edges[threadIdx.x];
  const int b = blockIdx.x >> 10, j = blockIdx.x & 1023;
  const float pj = (float)positions[b * SEQ + j];
  __syncthreads();
  const int i0 = threadIdx.x * 4;
  int4 pi4 = *reinterpret_cast<const int4*>(&positions[b * SEQ + i0]);
  unsigned out = 0;
#pragma unroll
  for (int r = 0; r < 4; ++r) {
    float pi = (float)((&pi4.x)[r]);
    float fd = fabsf(pj - pi);
    int bin = 0;
#pragma unroll
    for (int t = 0; t < 31; ++t) bin += (eg[t] < fd) ? 1 : 0;
    out |= (unsigned)bin << (8 * r);
  }
  *reinterpret_cast<unsigned*>(&bins[(size_t)(b * SEQ + j) * SEQ + i0]) = out;
}

// ---------------- QKV projection GEMM ----------------
// Q,K -> [b][h][n][d]; V -> TRANSPOSED [b][h][d][n]
__global__ __launch_bounds__(256) void qkv_gemm(const _Float16* __restrict__ xh,
                                                const _Float16* __restrict__ wh,
                                                const float* __restrict__ bias,
                                                _Float16* __restrict__ qkv) {
  __shared__ __attribute__((aligned(16))) _Float16 As[64 * 40];
  __shared__ __attribute__((aligned(16))) _Float16 Bs[64 * 40];
  const int m0 = blockIdx.x * 64, n0 = blockIdx.y * 64;
  const int tid = threadIdx.x, w = tid >> 6, lane = tid & 63;
  const int lr = lane & 15, lg = lane >> 4;
  f32x4 acc[4] = {};
  const int sr = tid >> 2, ss = (tid & 3) * 8;
  for (int k0 = 0; k0 < 512; k0 += 32) {
    *reinterpret_cast<uint4*>(&As[sr * 40 + ss]) =
        *reinterpret_cast<const uint4*>(&xh[(m0 + sr) * 512 + k0 + ss]);
    *reinterpret_cast<uint4*>(&Bs[sr * 40 + ss]) =
        *reinterpret_cast<const uint4*>(&wh[(n0 + sr) * 512 + k0 + ss]);
    __syncthreads();
    half8 a = *reinterpret_cast<const half8*>(&As[(w * 16 + lr) * 40 + lg * 8]);
#pragma unroll
    for (int ct = 0; ct < 4; ++ct) {
      half8 bf = *reinterpret_cast<const half8*>(&Bs[(ct * 16 + lr) * 40 + lg * 8]);
      acc[ct] = __builtin_amdgcn_mfma_f32_16x16x32_f16(a, bf, acc[ct], 0, 0, 0);
    }
    __syncthreads();
  }
  const int p = n0 >> 9;   // block-uniform: 0=Q,1=K,2=V
  if (p < 2) {
#pragma unroll
    for (int ct = 0; ct < 4; ++ct) {
      int n = n0 + ct * 16 + lr;
      float bv = bias[n];
      int c = n & 511, h = c >> 6, d = c & 63;
#pragma unroll
      for (int r = 0; r < 4; ++r) {
        int m = m0 + w * 16 + lg * 4 + r;
        int bb = m >> 10, nn = m & 1023;
        qkv[p * 4194304 + ((bb * NH + h) * SEQ + nn) * DH + d] = (_Float16)(acc[ct][r] + bv);
      }
    }
  } else {
#pragma unroll
    for (int ct = 0; ct < 4; ++ct) {
      int n = n0 + ct * 16 + lr;
      float bv = bias[n];
      int c = n & 511, h = c >> 6, d = c & 63;
      int m = m0 + w * 16 + lg * 4;
      int bb = m >> 10, nn = m & 1023;
      half4 st;
#pragma unroll
      for (int r = 0; r < 4; ++r) st[r] = (_Float16)(acc[ct][r] + bv);
      *reinterpret_cast<half4*>(&qkv[8388608 + (size_t)((bb * NH + h) * DH + d) * SEQ + nn]) = st;
    }
  }
}

// ---------------- fused attention (flash-style) ----------------
__global__ __launch_bounds__(256) void attn_kernel(const _Float16* __restrict__ qkv,
                                                   const int* __restrict__ positions,
                                                   const float* __restrict__ mask,
                                                   const unsigned char* __restrict__ bins,
                                                   const float* __restrict__ demb,
                                                   const float* __restrict__ order_bias,
                                                   _Float16* __restrict__ aout) {
  __shared__ __attribute__((aligned(16))) _Float16 Ks[64 * 72];
  __shared__ __attribute__((aligned(16))) _Float16 Vts[64 * 72];
  __shared__ __attribute__((aligned(16))) _Float16 Pl[64 * 72];
  __shared__ __attribute__((aligned(16))) unsigned char binsl[64 * 80];
  __shared__ float dembl[32];
  __shared__ int posq[64], poskv[64];
  __shared__ float maskq[64], maskkv[64];

  // XCD-chunked swizzle: 1024 blocks, 8 XCDs -> 128 consecutive work items per XCD
  const int lin = (blockIdx.x & 7) * 128 + (blockIdx.x >> 3);
  const int qt = lin & 15, h = (lin >> 4) & 7, b = lin >> 7;
  const int tid = threadIdx.x, w = tid >> 6, lane = tid & 63;
  const int lr = lane & 15, lg = lane >> 4;

  if (tid < 64) {
    posq[tid] = positions[b * SEQ + qt * 64 + tid];
    maskq[tid] = mask[b * SEQ + qt * 64 + tid];
  } else if (tid < 96) {
    dembl[tid - 64] = demb[(tid - 64) * NH + h];
  }

  const _Float16* Qg  = qkv + (size_t)((b * NH + h) * SEQ) * DH;
  const _Float16* Kg  = qkv + 4194304 + (size_t)((b * NH + h) * SEQ) * DH;
  const _Float16* Vtg = qkv + 8388608 + (size_t)((b * NH + h) * DH) * SEQ;

  half8 qf[2];
#pragma unroll
  for (int ks = 0; ks < 2; ++ks) {
    qf[ks] = *reinterpret_cast<const half8*>(&Qg[(qt * 64 + w * 16 + lr) * DH + ks * 32 + lg * 8]);
#pragma unroll
    for (int e = 0; e < 8; ++e) qf[ks][e] = qf[ks][e] * (_Float16)0.125f;   // fold 1/sqrt(64), exact
  }
  const float obh = 0.5f * order_bias[h];
  float m_run[4], l_run[4];
  f32x4 o[4] = {};
#pragma unroll
  for (int r = 0; r < 4; ++r) { m_run[r] = -INFINITY; l_run[r] = 0.f; }

  const int sr = tid >> 2, ss = (tid & 3) * 16;
  for (int kt = 0; kt < 16; ++kt) {
    const int kv0 = kt * 64;
    *reinterpret_cast<uint4*>(&Ks[sr * 72 + ss]) =
        *reinterpret_cast<const uint4*>(&Kg[(kv0 + sr) * DH + ss]);
    *reinterpret_cast<uint4*>(&Ks[sr * 72 + ss + 8]) =
        *reinterpret_cast<const uint4*>(&Kg[(kv0 + sr) * DH + ss + 8]);
    *reinterpret_cast<uint4*>(&Vts[sr * 72 + ss]) =
        *reinterpret_cast<const uint4*>(&Vtg[sr * SEQ + kv0 + ss]);
    *reinterpret_cast<uint4*>(&Vts[sr * 72 + ss + 8]) =
        *reinterpret_cast<const uint4*>(&Vtg[sr * SEQ + kv0 + ss + 8]);
    *reinterpret_cast<uint4*>(&binsl[sr * 80 + (tid & 3) * 16]) =
        *reinterpret_cast<const uint4*>(&bins[(size_t)(b * SEQ + kv0 + sr) * SEQ + qt * 64 + (tid & 3) * 16]);
    if (tid < 64) {
      poskv[tid] = positions[b * SEQ + kv0 + tid];
      maskkv[tid] = mask[b * SEQ + kv0 + tid];
    }
    __syncthreads();

    // accumulator init = dist bias + order bias (+ mask)
    f32x4 s4[4];
    int pi[4];
#pragma unroll
    for (int r = 0; r < 4; ++r) pi[r] = posq[w * 16 + lg * 4 + r];
#pragma unroll
    for (int ct = 0; ct < 4; ++ct) {
      const int col = ct * 16 + lr;
      const int pj = poskv[col];
      const float mv = maskkv[col];
      unsigned bw = *reinterpret_cast<const unsigned*>(&binsl[col * 80 + w * 16 + lg * 4]);
#pragma unroll
      for (int r = 0; r < 4; ++r) {
        float bias = dembl[(bw >> (8 * r)) & 255u];
        float sv = bias + ((pj > pi[r]) ? obh : -obh);
        s4[ct][r] = (mv == 0.f) ? -1.0e9f : sv;
      }
    }
    __builtin_amdgcn_s_setprio(1);
#pragma unroll
    for (int ct = 0; ct < 4; ++ct)
#pragma unroll
      for (int ks = 0; ks < 2; ++ks) {
        half8 bf = *reinterpret_cast<const half8*>(&Ks[(ct * 16 + lr) * 72 + ks * 32 + lg * 8]);
        s4[ct] = __builtin_amdgcn_mfma_f32_16x16x32_f16(qf[ks], bf, s4[ct], 0, 0, 0);
      }
    __builtin_amdgcn_s_setprio(0);

    // online softmax; l kept as per-lane partial (reduced once at the end)
#pragma unroll
    for (int r = 0; r < 4; ++r) {
      float m_ = fmaxf(fmaxf(s4[0][r], s4[1][r]), fmaxf(s4[2][r], s4[3][r]));
      m_ = fmaxf(m_, __shfl_xor(m_, 1)); m_ = fmaxf(m_, __shfl_xor(m_, 2));
      m_ = fmaxf(m_, __shfl_xor(m_, 4)); m_ = fmaxf(m_, __shfl_xor(m_, 8));
      float newm = fmaxf(m_run[r], m_);
      float alpha = __expf(m_run[r] - newm);
      m_run[r] = newm;
      float s_ = 0.f;
#pragma unroll
      for (int ct = 0; ct < 4; ++ct) {
        float pv = __expf(s4[ct][r] - newm);
        s4[ct][r] = pv; s_ += pv;
      }
      l_run[r] = l_run[r] * alpha + s_;
#pragma unroll
      for (int dt = 0; dt < 4; ++dt) o[dt][r] *= alpha;
    }
    // P -> LDS (wave-private rows: no barrier needed before PV)
#pragma unroll
    for (int ct = 0; ct < 4; ++ct)
#pragma unroll
      for (int r = 0; r < 4; ++r)
        Pl[(w * 16 + lg * 4 + r) * 72 + ct * 16 + lr] = (_Float16)s4[ct][r];
    __builtin_amdgcn_s_setprio(1);
#pragma unroll
    for (int dt = 0; dt < 4; ++dt)
#pragma unroll
      for (int ks = 0; ks < 2; ++ks) {
        half8 pa = *reinterpret_cast<const half8*>(&Pl[(w * 16 + lr) * 72 + ks * 32 + lg * 8]);
        half8 vb = *reinterpret_cast<const half8*>(&Vts[(dt * 16 + lr) * 72 + ks * 32 + lg * 8]);
        o[dt] = __builtin_amdgcn_mfma_f32_16x16x32_f16(pa, vb, o[dt], 0, 0, 0);
      }
    __builtin_amdgcn_s_setprio(0);
    __syncthreads();
  }
  float linv[4];
#pragma unroll
  for (int r = 0; r < 4; ++r) {
    float s_ = l_run[r];
    s_ += __shfl_xor(s_, 1); s_ += __shfl_xor(s_, 2);
    s_ += __shfl_xor(s_, 4); s_ += __shfl_xor(s_, 8);
    linv[r] = 1.0f / s_;
  }
#pragma unroll
  for (int dt = 0; dt < 4; ++dt) {
    int d = dt * 16 + lr;
#pragma unroll
    for (int r = 0; r < 4; ++r) {
      int qrow = w * 16 + lg * 4 + r;
      float val = o[dt][r] * linv[r] * maskq[qrow];
      aout[(size_t)(b * SEQ + qt * 64 + qrow) * DMODEL + h * DH + d] = (_Float16)val;
    }
  }
}

// ---------------- output projection GEMM ----------------
__global__ __launch_bounds__(256) void out_gemm(const _Float16* __restrict__ ah,
                                                const _Float16* __restrict__ wh,
                                                const float* __restrict__ ob,
                                                float* __restrict__ out) {
  __shared__ __attribute__((aligned(16))) _Float16 As[64 * 40];
  __shared__ __attribute__((aligned(16))) _Float16 Bs[64 * 40];
  const int m0 = blockIdx.x * 64, n0 = blockIdx.y * 64;
  const int tid = threadIdx.x, w = tid >> 6, lane = tid & 63;
  const int lr = lane & 15, lg = lane >> 4;
  f32x4 acc[4] = {};
  const int sr = tid >> 2, ss = (tid & 3) * 8;
  for (int k0 = 0; k0 < 512; k0 += 32) {
    *reinterpret_cast<uint4*>(&As[sr * 40 + ss]) =
        *reinterpret_cast<const uint4*>(&ah[(m0 + sr) * 512 + k0 + ss]);
    *reinterpret_cast<uint4*>(&Bs[sr * 40 + ss]) =
        *reinterpret_cast<const uint4*>(&wh[(n0 + sr) * 512 + k0 + ss]);
    __syncthreads();
    half8 a = *reinterpret_cast<const half8*>(&As[(w * 16 + lr) * 40 + lg * 8]);
#pragma unroll
    for (int ct = 0; ct < 4; ++ct) {
      half8 bf = *reinterpret_cast<const half8*>(&Bs[(ct * 16 + lr) * 40 + lg * 8]);
      acc[ct] = __builtin_amdgcn_mfma_f32_16x16x32_f16(a, bf, acc[ct], 0, 0, 0);
    }
    __syncthreads();
  }
#pragma unroll
  for (int ct = 0; ct < 4; ++ct) {
    int n = n0 + ct * 16 + lr;
    float bv = ob[n];
#pragma unroll
    for (int r = 0; r < 4; ++r) {
      int m = m0 + w * 16 + lg * 4 + r;
      out[m * DMODEL + n] = acc[ct][r] + bv;
    }
  }
}

extern "C" void kernel_launch(void* const* d_in, const int* in_sizes, int n_in,
                              void* d_out, int out_size, void* d_ws, size_t ws_size,
                              hipStream_t stream) {
  const float* x         = (const float*)d_in[0];
  const int*   positions = (const int*)d_in[1];
  const float* mask      = (const float*)d_in[2];
  const float* qw        = (const float*)d_in[3];
  const float* qb        = (const float*)d_in[4];
  const float* kw        = (const float*)d_in[5];
  const float* kb        = (const float*)d_in[6];
  const float* vw        = (const float*)d_in[7];
  const float* vb        = (const float*)d_in[8];
  const float* ow        = (const float*)d_in[9];
  const float* ob        = (const float*)d_in[10];
  const float* demb      = (const float*)d_in[11];
  const float* obias     = (const float*)d_in[12];
  const float* edges     = (const float*)d_in[13];

  char* ws = (char*)d_ws;
  _Float16* xh     = (_Float16*)(ws);                    // [0, 8MB)   (dead after qkv_gemm)
  unsigned char* bins = (unsigned char*)(ws);            // reuses xh region (8MB, after qkv_gemm)
  _Float16* qkv    = (_Float16*)(ws + 8388608);          // Q,K,[V^T]  24MB
  _Float16* aouth  = (_Float16*)(ws + 33554432);         // 8MB
  _Float16* wqkvh  = (_Float16*)(ws + 41943040);         // 1.5MB
  _Float16* owh    = (_Float16*)(ws + 43515904);         // 0.5MB
  float*    qkvbias= (float*)(ws + 44040192);            // 6KB
  float*    outp   = (float*)d_out;

  prep_cast_x<<<4096, 256, 0, stream>>>(x, xh);
  prep_w<<<1026, 256, 0, stream>>>(qw, kw, vw, ow, qb, kb, vb, wqkvh, owh, qkvbias);
  qkv_gemm<<<dim3(128, 24), 256, 0, stream>>>(xh, wqkvh, qkvbias, qkv);
  prep_bins<<<8192, 256, 0, stream>>>(positions, edges, bins);   // after qkv_gemm: overwrites xh
  attn_kernel<<<1024, 256, 0, stream>>>(qkv, positions, mask, bins, demb, obias, aouth);
  out_gemm<<<dim3(128, 8), 256, 0, stream>>>(aouth, owh, ob, outp);
}

// Round 3
// 118.118 us; speedup vs baseline: 1.3457x; 1.1839x over previous
//
#include <hip/hip_runtime.h>
#include <hip/hip_bf16.h>

#define SEQ   1024
#define NH    8
#define DH    64

typedef __attribute__((ext_vector_type(8))) _Float16 half8;
typedef __attribute__((ext_vector_type(4))) _Float16 half4;
typedef __attribute__((ext_vector_type(4))) float    f32x4;

#if __has_builtin(__builtin_amdgcn_exp2f)
#define EXP2F __builtin_amdgcn_exp2f
#else
#define EXP2F exp2f
#endif

__device__ inline unsigned pk2(float a, float b) {
  return __builtin_bit_cast(unsigned, __builtin_amdgcn_cvt_pkrtz(a, b));
}
__device__ inline void swap32(unsigned &a, unsigned &b) {
  asm("v_permlane32_swap_b32 %0, %1" : "+v"(a), "+v"(b));
}
__device__ inline void swap16(unsigned &a, unsigned &b) {
  asm("v_permlane16_swap_b32 %0, %1" : "+v"(a), "+v"(b));
}
__device__ inline half8 mk8(unsigned a, unsigned b, unsigned c, unsigned d) {
  union { unsigned u[4]; half8 h; } x;
  x.u[0] = a; x.u[1] = b; x.u[2] = c; x.u[3] = d;
  return x.h;
}

// ---------------- prep: cast x to fp16 ----------------
__global__ void prep_cast_x(const float* __restrict__ x, _Float16* __restrict__ xh) {
  int g = blockIdx.x * 256 + threadIdx.x;
  float4 v = reinterpret_cast<const float4*>(x)[g];
  half4 u;
  u[0] = (_Float16)v.x; u[1] = (_Float16)v.y; u[2] = (_Float16)v.z; u[3] = (_Float16)v.w;
  reinterpret_cast<half4*>(xh)[g] = u;
}

// ---------------- prep: weights + bias concat ----------------
__global__ void prep_w(const float* __restrict__ qw, const float* __restrict__ kw,
                       const float* __restrict__ vw, const float* __restrict__ ow,
                       const float* __restrict__ qb, const float* __restrict__ kb,
                       const float* __restrict__ vb,
                       _Float16* __restrict__ wqkvh, _Float16* __restrict__ owh,
                       float* __restrict__ qkvbias) {
  int g = blockIdx.x * 256 + threadIdx.x;
  if (g < 196608) {
    const float* src = (g < 65536) ? qw : (g < 131072) ? kw : vw;
    int lg = g & 65535;
    float4 v = reinterpret_cast<const float4*>(src)[lg];
    half4 u;
    u[0] = (_Float16)v.x; u[1] = (_Float16)v.y; u[2] = (_Float16)v.z; u[3] = (_Float16)v.w;
    reinterpret_cast<half4*>(wqkvh)[g] = u;
  } else if (g < 262144) {
    int lg = g - 196608;
    float4 v = reinterpret_cast<const float4*>(ow)[lg];
    half4 u;
    u[0] = (_Float16)v.x; u[1] = (_Float16)v.y; u[2] = (_Float16)v.z; u[3] = (_Float16)v.w;
    reinterpret_cast<half4*>(owh)[lg] = u;
  } else if (g < 262528) {
    int lg = g - 262144;
    const float* src = (lg < 128) ? qb : (lg < 256) ? kb : vb;
    int ll = lg & 127;
    reinterpret_cast<float4*>(qkvbias)[lg] = reinterpret_cast<const float4*>(src)[ll];
  }
}

// ---------------- prep: integer-distance -> bin LUT (searchsorted side='left') ----------------
__global__ void prep_lutd(const float* __restrict__ edges, unsigned char* __restrict__ lutd) {
  int d = blockIdx.x * 256 + threadIdx.x;   // 0..5119
  float fd = (float)d;
  int bin = 0;
#pragma unroll
  for (int t = 0; t < 31; ++t) bin += (edges[t] < fd) ? 1 : 0;
  lutd[d] = (unsigned char)bin;
}

// ---------------- prep: ebins[b][r][c] = bin | (p_c>p_r)<<5 | (mask_c==0)<<6 ----------------
__global__ __launch_bounds__(256) void prep_ebins(const int* __restrict__ positions,
                                                  const float* __restrict__ mask,
                                                  const unsigned char* __restrict__ lutd,
                                                  unsigned char* __restrict__ ebins) {
  __shared__ unsigned char lutl[5120];
  __shared__ int posl[SEQ];
  __shared__ unsigned char mk[SEQ];
  const int b = blockIdx.x >> 8, j0 = (blockIdx.x & 255) * 4;
  const int tid = threadIdx.x;
  for (int i = tid; i < 1280; i += 256)
    reinterpret_cast<unsigned*>(lutl)[i] = reinterpret_cast<const unsigned*>(lutd)[i];
  for (int i = tid; i < SEQ; i += 256) {
    posl[i] = positions[b * SEQ + i];
    mk[i] = (mask[b * SEQ + i] == 0.f) ? 64 : 0;
  }
  __syncthreads();
  const int c0 = tid * 4;
#pragma unroll
  for (int jj = 0; jj < 4; ++jj) {
    const int j = j0 + jj;
    const int pr = posl[j];
    unsigned out = 0;
#pragma unroll
    for (int r = 0; r < 4; ++r) {
      int c = c0 + r;
      int pc = posl[c];
      int d = pc - pr; d = d < 0 ? -d : d;
      if (d > 5119) d = 5119;
      unsigned e = lutl[d] | ((pc > pr) ? 32u : 0u) | (unsigned)mk[c];
      out |= e << (8 * r);
    }
    reinterpret_cast<unsigned*>(&ebins[(size_t)(b * SEQ + j) * SEQ])[tid] = out;
  }
}

// ---------------- QKV projection GEMM (128x128 tile, BK=64) ----------------
// Q -> [b][h][n][d] * 0.125 ; K -> [b][h][n][d] * log2(e) ; V -> transposed [b][h][d][n]
__global__ __launch_bounds__(256) void qkv_gemm2(const _Float16* __restrict__ xh,
                                                 const _Float16* __restrict__ wh,
                                                 const float* __restrict__ bias,
                                                 _Float16* __restrict__ qkv) {
  __shared__ __attribute__((aligned(16))) _Float16 As[128 * 72];
  __shared__ __attribute__((aligned(16))) _Float16 Bs[128 * 72];
  const int m0 = blockIdx.x * 128, n0 = blockIdx.y * 128;
  const int tid = threadIdx.x, w = tid >> 6, lane = tid & 63;
  const int lr = lane & 15, lg = lane >> 4;
  const int wr = (w >> 1) * 64, wc = (w & 1) * 64;
  f32x4 acc[4][4] = {};
  const int srow = tid >> 1, sseg = (tid & 1) * 32;
  for (int k0 = 0; k0 < 512; k0 += 64) {
#pragma unroll
    for (int s = 0; s < 4; ++s) {
      *reinterpret_cast<uint4*>(&As[srow * 72 + sseg + s * 8]) =
          *reinterpret_cast<const uint4*>(&xh[(m0 + srow) * 512 + k0 + sseg + s * 8]);
      *reinterpret_cast<uint4*>(&Bs[srow * 72 + sseg + s * 8]) =
          *reinterpret_cast<const uint4*>(&wh[(n0 + srow) * 512 + k0 + sseg + s * 8]);
    }
    __syncthreads();
#pragma unroll
    for (int kk = 0; kk < 2; ++kk) {
      half8 af[4], bf[4];
#pragma unroll
      for (int mt = 0; mt < 4; ++mt)
        af[mt] = *reinterpret_cast<const half8*>(&As[(wr + mt * 16 + lr) * 72 + kk * 32 + lg * 8]);
#pragma unroll
      for (int nt = 0; nt < 4; ++nt)
        bf[nt] = *reinterpret_cast<const half8*>(&Bs[(wc + nt * 16 + lr) * 72 + kk * 32 + lg * 8]);
#pragma unroll
      for (int mt = 0; mt < 4; ++mt)
#pragma unroll
        for (int nt = 0; nt < 4; ++nt)
          acc[mt][nt] = __builtin_amdgcn_mfma_f32_16x16x32_f16(af[mt], bf[nt], acc[mt][nt], 0, 0, 0);
    }
    __syncthreads();
  }
  const int p = n0 >> 9;   // block-uniform: 0=Q,1=K,2=V
  const float scl = (p == 0) ? 0.125f : (p == 1) ? 1.44269504f : 1.0f;
  if (p < 2) {
#pragma unroll
    for (int nt = 0; nt < 4; ++nt) {
      int n = n0 + wc + nt * 16 + lr;
      float bv = bias[n];
      int c = n & 511, h = c >> 6, d = c & 63;
#pragma unroll
      for (int mt = 0; mt < 4; ++mt)
#pragma unroll
        for (int r = 0; r < 4; ++r) {
          int m = m0 + wr + mt * 16 + lg * 4 + r;
          int bb = m >> 10, nn = m & 1023;
          qkv[p * 4194304 + ((bb * NH + h) * SEQ + nn) * DH + d] = (_Float16)((acc[mt][nt][r] + bv) * scl);
        }
    }
  } else {
#pragma unroll
    for (int nt = 0; nt < 4; ++nt) {
      int n = n0 + wc + nt * 16 + lr;
      float bv = bias[n];
      int c = n & 511, h = c >> 6, d = c & 63;
#pragma unroll
      for (int mt = 0; mt < 4; ++mt) {
        int m = m0 + wr + mt * 16 + lg * 4;
        int bb = m >> 10, nn = m & 1023;
        half4 st;
#pragma unroll
        for (int r = 0; r < 4; ++r) st[r] = (_Float16)(acc[mt][nt][r] + bv);
        *reinterpret_cast<half4*>(&qkv[8388608 + ((bb * NH + h) * DH + d) * SEQ + nn]) = st;
      }
    }
  }
}

// ---------------- fused attention: swapped-S^T, in-register P, dbuf K/V ----------------
__global__ __launch_bounds__(256) void attn2(const _Float16* __restrict__ qkv,
                                             const float* __restrict__ mask,
                                             const unsigned char* __restrict__ ebins,
                                             const float* __restrict__ demb,
                                             const float* __restrict__ obias,
                                             _Float16* __restrict__ aout) {
  __shared__ __attribute__((aligned(16))) _Float16 KsBuf[2][64 * 72];
  __shared__ __attribute__((aligned(16))) _Float16 VtBuf[2][64 * 72];
  __shared__ float elutl[128];

  const int blk = blockIdx.x;                     // 512 blocks
  const int lin = (blk & 7) * 64 + (blk >> 3);    // XCD-chunked
  const int qt = lin & 7, h = (lin >> 3) & 7, b = lin >> 6;
  const int tid = threadIdx.x, w = tid >> 6, lane = tid & 63;
  const int lr = lane & 15, lg = lane >> 4;

  if (tid < 128) {
    float v;
    if (tid & 64) v = -1.442695e9f;
    else v = (demb[(tid & 31) * NH + h] + ((tid & 32) ? 0.5f : -0.5f) * obias[h]) * 1.44269504f;
    elutl[tid] = v;
  }

  const _Float16* Qg  = qkv + (size_t)(b * NH + h) * 65536;
  const _Float16* Kg  = qkv + 4194304 + (size_t)(b * NH + h) * 65536;
  const _Float16* Vtg = qkv + 8388608 + (size_t)(b * NH + h) * 65536;

  const int q_base = qt * 128 + w * 32;
  half8 qf[2][2];
#pragma unroll
  for (int qc = 0; qc < 2; ++qc)
#pragma unroll
    for (int ks = 0; ks < 2; ++ks)
      qf[qc][ks] = *reinterpret_cast<const half8*>(&Qg[(q_base + qc * 16 + lr) * DH + ks * 32 + lg * 8]);
  float mq[2];
#pragma unroll
  for (int qc = 0; qc < 2; ++qc) mq[qc] = mask[b * SEQ + q_base + qc * 16 + lr];

  float m_run[2] = {-INFINITY, -INFINITY}, l_run[2] = {0.f, 0.f};
  f32x4 o[4][2] = {};

  const int sr = tid >> 2, sc = (tid & 3) * 16;
  // stage tile 0 into buf 0
  *reinterpret_cast<uint4*>(&KsBuf[0][sr * 72 + sc]) =
      *reinterpret_cast<const uint4*>(&Kg[sr * DH + sc]);
  *reinterpret_cast<uint4*>(&KsBuf[0][sr * 72 + sc + 8]) =
      *reinterpret_cast<const uint4*>(&Kg[sr * DH + sc + 8]);
  *reinterpret_cast<uint4*>(&VtBuf[0][sr * 72 + sc]) =
      *reinterpret_cast<const uint4*>(&Vtg[sr * SEQ + sc]);
  *reinterpret_cast<uint4*>(&VtBuf[0][sr * 72 + sc + 8]) =
      *reinterpret_cast<const uint4*>(&Vtg[sr * SEQ + sc + 8]);
  __syncthreads();

  for (int kt = 0; kt < 16; ++kt) {
    const int cur = kt & 1;
    // (a) issue next-tile global loads early (latency hides under QK+softmax)
    uint4 kA, kB, vA, vB;
    if (kt < 15) {
      const int kv = (kt + 1) * 64;
      kA = *reinterpret_cast<const uint4*>(&Kg[(kv + sr) * DH + sc]);
      kB = *reinterpret_cast<const uint4*>(&Kg[(kv + sr) * DH + sc + 8]);
      vA = *reinterpret_cast<const uint4*>(&Vtg[sr * SEQ + kv + sc]);
      vB = *reinterpret_cast<const uint4*>(&Vtg[sr * SEQ + kv + sc + 8]);
    }
    // (b) accumulator init from ebin bytes (bias+sign+mask, exp2-scaled)
    f32x4 s4t[4][2];
#pragma unroll
    for (int ct = 0; ct < 4; ++ct)
#pragma unroll
      for (int qc = 0; qc < 2; ++qc) {
        unsigned ebw = *reinterpret_cast<const unsigned*>(
            &ebins[(size_t)(b * SEQ + q_base + qc * 16 + lr) * SEQ + kt * 64 + ct * 16 + lg * 4]);
        s4t[ct][qc][0] = elutl[ebw & 127u];
        s4t[ct][qc][1] = elutl[(ebw >> 8) & 127u];
        s4t[ct][qc][2] = elutl[(ebw >> 16) & 127u];
        s4t[ct][qc][3] = elutl[(ebw >> 24) & 127u];
      }
    // QK^T swapped: S^T tile, row=k col=q
    __builtin_amdgcn_s_setprio(1);
#pragma unroll
    for (int ct = 0; ct < 4; ++ct) {
      half8 kf0 = *reinterpret_cast<const half8*>(&KsBuf[cur][(ct * 16 + lr) * 72 + lg * 8]);
      half8 kf1 = *reinterpret_cast<const half8*>(&KsBuf[cur][(ct * 16 + lr) * 72 + 32 + lg * 8]);
#pragma unroll
      for (int qc = 0; qc < 2; ++qc) {
        s4t[ct][qc] = __builtin_amdgcn_mfma_f32_16x16x32_f16(kf0, qf[qc][0], s4t[ct][qc], 0, 0, 0);
        s4t[ct][qc] = __builtin_amdgcn_mfma_f32_16x16x32_f16(kf1, qf[qc][1], s4t[ct][qc], 0, 0, 0);
      }
    }
    __builtin_amdgcn_s_setprio(0);
    // online softmax: per lane, q = q_base + qc*16 + lr; 16 own k-slots; reduce over lg
    unsigned W[2][4][2];
#pragma unroll
    for (int qc = 0; qc < 2; ++qc) {
      float m_ = s4t[0][qc][0];
#pragma unroll
      for (int ct = 0; ct < 4; ++ct)
#pragma unroll
        for (int r = 0; r < 4; ++r) m_ = fmaxf(m_, s4t[ct][qc][r]);
      m_ = fmaxf(m_, __shfl_xor(m_, 16));
      m_ = fmaxf(m_, __shfl_xor(m_, 32));
      float newm = fmaxf(m_run[qc], m_);
      float alpha = EXP2F(m_run[qc] - newm);
      m_run[qc] = newm;
      float s_ = 0.f;
#pragma unroll
      for (int ct = 0; ct < 4; ++ct)
#pragma unroll
        for (int r = 0; r < 4; ++r) {
          float pv = EXP2F(s4t[ct][qc][r] - newm);
          s4t[ct][qc][r] = pv; s_ += pv;
        }
      l_run[qc] = l_run[qc] * alpha + s_;
#pragma unroll
      for (int dt = 0; dt < 4; ++dt) o[dt][qc] *= alpha;
      // pack to fp16 pairs
#pragma unroll
      for (int ct = 0; ct < 4; ++ct) {
        W[qc][ct][0] = pk2(s4t[ct][qc][0], s4t[ct][qc][1]);
        W[qc][ct][1] = pk2(s4t[ct][qc][2], s4t[ct][qc][3]);
      }
      // redistribute: lane bits (p2,p1) -> (p3,p2)  [reg-bit swaps]
#pragma unroll
      for (int u = 0; u < 2; ++u) {
        swap32(W[qc][0][u], W[qc][1][u]);
        swap32(W[qc][2][u], W[qc][3][u]);
      }
#pragma unroll
      for (int u = 0; u < 2; ++u) {
        swap16(W[qc][0][u], W[qc][1][u]);
        swap16(W[qc][2][u], W[qc][3][u]);
      }
    }
    // (c) write next tile to other LDS buffer
    if (kt < 15) {
      *reinterpret_cast<uint4*>(&KsBuf[cur ^ 1][sr * 72 + sc]) = kA;
      *reinterpret_cast<uint4*>(&KsBuf[cur ^ 1][sr * 72 + sc + 8]) = kB;
      *reinterpret_cast<uint4*>(&VtBuf[cur ^ 1][sr * 72 + sc]) = vA;
      *reinterpret_cast<uint4*>(&VtBuf[cur ^ 1][sr * 72 + sc + 8]) = vB;
    }
    // (d) PV swapped: o^T[d][q] += Vt-frag x P-frag
    __builtin_amdgcn_s_setprio(1);
#pragma unroll
    for (int ks = 0; ks < 2; ++ks) {
      half8 pa[2];
#pragma unroll
      for (int qc = 0; qc < 2; ++qc)
        pa[qc] = mk8(W[qc][ks * 2][0], W[qc][ks * 2][1], W[qc][ks * 2 + 1][0], W[qc][ks * 2 + 1][1]);
#pragma unroll
      for (int dt = 0; dt < 4; ++dt) {
        half8 vf = *reinterpret_cast<const half8*>(&VtBuf[cur][(dt * 16 + lr) * 72 + ks * 32 + lg * 8]);
#pragma unroll
        for (int qc = 0; qc < 2; ++qc)
          o[dt][qc] = __builtin_amdgcn_mfma_f32_16x16x32_f16(vf, pa[qc], o[dt][qc], 0, 0, 0);
      }
    }
    __builtin_amdgcn_s_setprio(0);
    __syncthreads();
  }

  float linv[2];
#pragma unroll
  for (int qc = 0; qc < 2; ++qc) {
    float s_ = l_run[qc];
    s_ += __shfl_xor(s_, 16);
    s_ += __shfl_xor(s_, 32);
    linv[qc] = mq[qc] / s_;
  }
#pragma unroll
  for (int dt = 0; dt < 4; ++dt)
#pragma unroll
    for (int qc = 0; qc < 2; ++qc) {
      half4 st;
#pragma unroll
      for (int r = 0; r < 4; ++r) st[r] = (_Float16)(o[dt][qc][r] * linv[qc]);
      *reinterpret_cast<half4*>(
          &aout[(size_t)(b * SEQ + q_base + qc * 16 + lr) * 512 + h * DH + dt * 16 + lg * 4]) = st;
    }
}

// ---------------- output projection GEMM (128x128 tile, BK=64) ----------------
__global__ __launch_bounds__(256) void out_gemm2(const _Float16* __restrict__ ah,
                                                 const _Float16* __restrict__ wh,
                                                 const float* __restrict__ ob,
                                                 float* __restrict__ out) {
  __shared__ __attribute__((aligned(16))) _Float16 As[128 * 72];
  __shared__ __attribute__((aligned(16))) _Float16 Bs[128 * 72];
  const int m0 = blockIdx.x * 128, n0 = blockIdx.y * 128;
  const int tid = threadIdx.x, w = tid >> 6, lane = tid & 63;
  const int lr = lane & 15, lg = lane >> 4;
  const int wr = (w >> 1) * 64, wc = (w & 1) * 64;
  f32x4 acc[4][4] = {};
  const int srow = tid >> 1, sseg = (tid & 1) * 32;
  for (int k0 = 0; k0 < 512; k0 += 64) {
#pragma unroll
    for (int s = 0; s < 4; ++s) {
      *reinterpret_cast<uint4*>(&As[srow * 72 + sseg + s * 8]) =
          *reinterpret_cast<const uint4*>(&ah[(m0 + srow) * 512 + k0 + sseg + s * 8]);
      *reinterpret_cast<uint4*>(&Bs[srow * 72 + sseg + s * 8]) =
          *reinterpret_cast<const uint4*>(&wh[(n0 + srow) * 512 + k0 + sseg + s * 8]);
    }
    __syncthreads();
#pragma unroll
    for (int kk = 0; kk < 2; ++kk) {
      half8 af[4], bf[4];
#pragma unroll
      for (int mt = 0; mt < 4; ++mt)
        af[mt] = *reinterpret_cast<const half8*>(&As[(wr + mt * 16 + lr) * 72 + kk * 32 + lg * 8]);
#pragma unroll
      for (int nt = 0; nt < 4; ++nt)
        bf[nt] = *reinterpret_cast<const half8*>(&Bs[(wc + nt * 16 + lr) * 72 + kk * 32 + lg * 8]);
#pragma unroll
      for (int mt = 0; mt < 4; ++mt)
#pragma unroll
        for (int nt = 0; nt < 4; ++nt)
          acc[mt][nt] = __builtin_amdgcn_mfma_f32_16x16x32_f16(af[mt], bf[nt], acc[mt][nt], 0, 0, 0);
    }
    __syncthreads();
  }
#pragma unroll
  for (int nt = 0; nt < 4; ++nt) {
    int n = n0 + wc + nt * 16 + lr;
    float bv = ob[n];
#pragma unroll
    for (int mt = 0; mt < 4; ++mt)
#pragma unroll
      for (int r = 0; r < 4; ++r) {
        int m = m0 + wr + mt * 16 + lg * 4 + r;
        out[m * 512 + n] = acc[mt][nt][r] + bv;
      }
  }
}

extern "C" void kernel_launch(void* const* d_in, const int* in_sizes, int n_in,
                              void* d_out, int out_size, void* d_ws, size_t ws_size,
                              hipStream_t stream) {
  const float* x         = (const float*)d_in[0];
  const int*   positions = (const int*)d_in[1];
  const float* mask      = (const float*)d_in[2];
  const float* qw        = (const float*)d_in[3];
  const float* qb        = (const float*)d_in[4];
  const float* kw        = (const float*)d_in[5];
  const float* kb        = (const float*)d_in[6];
  const float* vw        = (const float*)d_in[7];
  const float* vb        = (const float*)d_in[8];
  const float* ow        = (const float*)d_in[9];
  const float* ob        = (const float*)d_in[10];
  const float* demb      = (const float*)d_in[11];
  const float* obias     = (const float*)d_in[12];
  const float* edges     = (const float*)d_in[13];

  char* ws = (char*)d_ws;
  _Float16* xh        = (_Float16*)(ws);                  // [0, 8M) — dead after qkv_gemm2
  unsigned char* ebins = (unsigned char*)(ws);            // reuses xh region after qkv_gemm2
  _Float16* qkv       = (_Float16*)(ws + 8388608);        // Q | K*log2e | V^T  (24 MB)
  _Float16* aouth     = (_Float16*)(ws + 33554432);       // 8 MB
  _Float16* wqkvh     = (_Float16*)(ws + 41943040);       // 1.5 MB
  _Float16* owh       = (_Float16*)(ws + 43515904);       // 0.5 MB
  float*    qkvbias   = (float*)(ws + 44040192);          // 6 KB
  unsigned char* lutd = (unsigned char*)(ws + 44046336);  // 5120 B
  float*    outp      = (float*)d_out;

  prep_cast_x<<<4096, 256, 0, stream>>>(x, xh);
  prep_w<<<1026, 256, 0, stream>>>(qw, kw, vw, ow, qb, kb, vb, wqkvh, owh, qkvbias);
  prep_lutd<<<20, 256, 0, stream>>>(edges, lutd);
  qkv_gemm2<<<dim3(64, 12), 256, 0, stream>>>(xh, wqkvh, qkvbias, qkv);
  prep_ebins<<<2048, 256, 0, stream>>>(positions, mask, lutd, ebins);  // overwrites xh region
  attn2<<<512, 256, 0, stream>>>(qkv, mask, ebins, demb, obias, aouth);
  out_gemm2<<<dim3(64, 4), 256, 0, stream>>>(aouth, owh, ob, outp);
}